// Round 3
// baseline (869.728 us; speedup 1.0000x reference)
//
#include <hip/hip_runtime.h>

#define NB 4
#define SEQ 4096
#define DM 512
#define DA 64

typedef __attribute__((ext_vector_type(8))) short bf16x8;
typedef __attribute__((ext_vector_type(4))) float f32x4;

__device__ __forceinline__ unsigned short f2bf(float f) {
  unsigned u = __float_as_uint(f);
  u += 0x7fffu + ((u >> 16) & 1u);
  return (unsigned short)(u >> 16);
}

__device__ __forceinline__ unsigned cvt_pk_bf16(float lo, float hi) {
  unsigned r;
  asm("v_cvt_pk_bf16_f32 %0, %1, %2" : "=v"(r) : "v"(lo), "v"(hi));
  return r;
}

// ---------------- Kernel 1: cast x (f32) -> xb (bf16) ----------------
__global__ void cast_x_kernel(const float* __restrict__ x, unsigned short* __restrict__ xb) {
  size_t i = ((size_t)blockIdx.x * blockDim.x + threadIdx.x) * 4;
  float4 v = *(const float4*)(x + i);
  ushort4 o;
  o.x = f2bf(v.x); o.y = f2bf(v.y); o.z = f2bf(v.z); o.w = f2bf(v.w);
  *(ushort4*)(xb + i) = o;
}

// ------------- Kernel 2: build Wt[640][512] bf16 (transposed) + bias[640] -------------
__global__ void prep_w_kernel(const float* __restrict__ Wq, const float* __restrict__ bq,
                              const float* __restrict__ Wk, const float* __restrict__ bk,
                              const float* __restrict__ Wv, const float* __restrict__ bv,
                              unsigned short* __restrict__ Wt, float* __restrict__ bias) {
  int n = blockIdx.x;  // 0..639
  for (int k = threadIdx.x; k < DM; k += blockDim.x) {
    float w;
    if (n < 64)       w = Wq[(size_t)k * DA + n];
    else if (n < 128) w = Wk[(size_t)k * DA + (n - 64)];
    else              w = Wv[(size_t)k * DM + (n - 128)];
    Wt[(size_t)n * DM + k] = f2bf(w);
  }
  if (threadIdx.x == 0)
    bias[n] = (n < 64) ? bq[n] : (n < 128) ? bk[n - 64] : bv[n - 128];
}

// ------------- Kernel 3: projection GEMM  out[16384 x 640] = xb @ Wt^T + bias -------------
// n<64 -> q[S][64], n<128 -> k[S][64], else vt[512][S] transposed V with keys
// PERMUTED within each 32-chunk: key c -> pos 8g+j so attn's PV A-frag needs no shuffle.
__launch_bounds__(256)
__global__ void proj_kernel(const unsigned short* __restrict__ xb,
                            const unsigned short* __restrict__ Wt,
                            const float* __restrict__ bias,
                            unsigned short* __restrict__ qws,
                            unsigned short* __restrict__ kws,
                            unsigned short* __restrict__ vt) {
  int ctb = blockIdx.x;
  int rtb = blockIdx.y;
  int tid = threadIdx.x;
  int wid = tid >> 6, lane = tid & 63;
  int g = lane >> 4, c15 = lane & 15;
  int wr = wid >> 1, wc = wid & 1;
  int rbase = rtb * 64 + wr * 32;
  int cbase = ctb * 64 + wc * 32;

  f32x4 acc[2][2];
  for (int i = 0; i < 2; i++) for (int j = 0; j < 2; j++) acc[i][j] = (f32x4)0.0f;

  for (int kk = 0; kk < DM; kk += 32) {
    bf16x8 a[2], bb[2];
    for (int i = 0; i < 2; i++)
      a[i] = *(const bf16x8*)(xb + (size_t)(rbase + i * 16 + c15) * DM + kk + g * 8);
    for (int j = 0; j < 2; j++)
      bb[j] = *(const bf16x8*)(Wt + (size_t)(cbase + j * 16 + c15) * DM + kk + g * 8);
    for (int i = 0; i < 2; i++)
      for (int j = 0; j < 2; j++)
        acc[i][j] = __builtin_amdgcn_mfma_f32_16x16x32_bf16(a[i], bb[j], acc[i][j], 0, 0, 0);
  }

  for (int i = 0; i < 2; i++) {
    for (int j = 0; j < 2; j++) {
      int n = cbase + j * 16 + c15;
      float bv_ = bias[n];
      for (int r = 0; r < 4; r++) {
        int R = rbase + i * 16 + g * 4 + r;
        float val = acc[i][j][r] + bv_;
        unsigned short h = f2bf(val);
        if (n < 64)        qws[(size_t)R * DA + n] = h;
        else if (n < 128)  kws[(size_t)R * DA + (n - 64)] = h;
        else {
          int b = R >> 12, s = R & (SEQ - 1);
          int c = s & 31;
          int pos = (c < 16) ? (((c >> 2) << 3) | (c & 3))
                             : ((((c & 15) >> 2) << 3) | 4 | (c & 3));
          vt[((size_t)b * DM + (n - 128)) * SEQ + (s & ~31) + pos] = h;
        }
      }
    }
  }
}

// ------------- Kernel 4: causal flash attention, S^T layout, zero LDS -------------
// Grid: (64 qblk-pairs, 4 dv-chunks, B). Block = 4 independent waves, 16 q-rows each.
// S^T = mfma(K,Q): lane (g,c15) holds P[q=c15][keys ct*16+4g+r]. Softmax = in-lane
// + 2 shfl_xor. P packed in-register (cvt_pk) feeds PV directly (V keys pre-permuted).
__launch_bounds__(256)
__global__ void attn_kernel(const unsigned short* __restrict__ qws,
                            const unsigned short* __restrict__ kws,
                            const unsigned short* __restrict__ vt,
                            float* __restrict__ ows) {
  int b = blockIdx.z;
  int dvb = blockIdx.y * 128;
  int bx = blockIdx.x;
  int qblk = (bx & 1) ? (63 - (bx >> 1)) : (bx >> 1);
  int tid = threadIdx.x;
  int wid = tid >> 6, lane = tid & 63;
  int g = lane >> 4, c15 = lane & 15;
  int qrow16 = qblk * 64 + wid * 16;
  int qsrc = (g << 4) | (g << 2);  // + r = lane holding stats for q-row g*4+r

  const unsigned short* kbase = kws + (size_t)b * SEQ * DA + (size_t)c15 * DA + g * 8;
  const unsigned short* vbase = vt + ((size_t)b * DM + dvb + c15) * SEQ + g * 8;

  bf16x8 qf[2];
  for (int kc2 = 0; kc2 < 2; kc2++)
    qf[kc2] = *(const bf16x8*)(qws + ((size_t)b * SEQ + qrow16 + c15) * DA + kc2 * 32 + g * 8);

  f32x4 acc[8];
  for (int n = 0; n < 8; n++) acc[n] = (f32x4)0.0f;
  float m_run = -1e30f, l_run = 0.0f;

  int nkt = (qrow16 + 16 + 127) >> 7;
  int ktEnd = (nkt - 1) * 128;

  auto iter = [&](int kt, bool domask) {
    f32x4 sc[8];
    for (int ct = 0; ct < 8; ct++) sc[ct] = (f32x4)0.0f;
    for (int kc2 = 0; kc2 < 2; kc2++)
      for (int ct = 0; ct < 8; ct++) {
        bf16x8 kf = *(const bf16x8*)(kbase + (size_t)(kt + ct * 16) * DA + kc2 * 32);
        sc[ct] = __builtin_amdgcn_mfma_f32_16x16x32_bf16(kf, qf[kc2], sc[ct], 0, 0, 0);
      }
    if (domask) {
      int qrow = qrow16 + c15;
      for (int ct = 0; ct < 8; ct++)
        for (int r = 0; r < 4; r++)
          if (kt + ct * 16 + g * 4 + r > qrow) sc[ct][r] = -1e30f;
    }
    float mv = -1e30f;
    for (int ct = 0; ct < 8; ct++)
      for (int r = 0; r < 4; r++) mv = fmaxf(mv, sc[ct][r]);
    mv = fmaxf(mv, __shfl_xor(mv, 16));
    mv = fmaxf(mv, __shfl_xor(mv, 32));
    float mn = fmaxf(m_run, mv);
    float sum = 0.0f;
    for (int ct = 0; ct < 8; ct++)
      for (int r = 0; r < 4; r++) {
        float p = __expf(sc[ct][r] - mn);
        sc[ct][r] = p;
        sum += p;
      }
    sum += __shfl_xor(sum, 16);
    sum += __shfl_xor(sum, 32);
    float scl = __expf(m_run - mn);
    m_run = mn;
    l_run = l_run * scl + sum;
    float sclr[4];
    for (int r = 0; r < 4; r++) sclr[r] = __shfl(scl, qsrc + r);
    for (int n = 0; n < 8; n++)
      for (int r = 0; r < 4; r++) acc[n][r] *= sclr[r];
    for (int kc = 0; kc < 4; kc++) {
      union { int i[4]; bf16x8 h; } pu;
      pu.i[0] = cvt_pk_bf16(sc[2 * kc][0], sc[2 * kc][1]);
      pu.i[1] = cvt_pk_bf16(sc[2 * kc][2], sc[2 * kc][3]);
      pu.i[2] = cvt_pk_bf16(sc[2 * kc + 1][0], sc[2 * kc + 1][1]);
      pu.i[3] = cvt_pk_bf16(sc[2 * kc + 1][2], sc[2 * kc + 1][3]);
      bf16x8 pa = pu.h;
      for (int n = 0; n < 8; n++) {
        bf16x8 vb = *(const bf16x8*)(vbase + (size_t)(n * 16) * SEQ + kt + kc * 32);
        acc[n] = __builtin_amdgcn_mfma_f32_16x16x32_bf16(pa, vb, acc[n], 0, 0, 0);
      }
    }
  };

  for (int kt = 0; kt < ktEnd; kt += 128) iter(kt, false);
  iter(ktEnd, true);

  float inv[4];
  for (int r = 0; r < 4; r++) inv[r] = 1.0f / __shfl(l_run, qsrc + r);
  for (int n = 0; n < 8; n++)
    for (int r = 0; r < 4; r++)
      ows[((size_t)b * SEQ + qrow16 + g * 4 + r) * DM + dvb + n * 16 + c15] = acc[n][r] * inv[r];
}

// ------------- Kernel 5: residual + LayerNorm (wave per row) -------------
__launch_bounds__(256)
__global__ void ln_kernel(const float* __restrict__ x, const float* __restrict__ o,
                          const float* __restrict__ gamma, const float* __restrict__ beta,
                          float* __restrict__ out) {
  int wid = threadIdx.x >> 6, lane = threadIdx.x & 63;
  size_t row = (size_t)blockIdx.x * 4 + wid;
  size_t base = row * DM + lane * 8;
  float4 xa = *(const float4*)(x + base);
  float4 xb2 = *(const float4*)(x + base + 4);
  float4 oa = *(const float4*)(o + base);
  float4 ob = *(const float4*)(o + base + 4);
  float y[8] = {xa.x + oa.x, xa.y + oa.y, xa.z + oa.z, xa.w + oa.w,
                xb2.x + ob.x, xb2.y + ob.y, xb2.z + ob.z, xb2.w + ob.w};
  float s1 = 0.0f, s2 = 0.0f;
  for (int j = 0; j < 8; j++) { s1 += y[j]; s2 += y[j] * y[j]; }
  for (int m = 1; m < 64; m <<= 1) { s1 += __shfl_xor(s1, m); s2 += __shfl_xor(s2, m); }
  float mu = s1 * (1.0f / DM);
  float var = s2 * (1.0f / DM) - mu * mu;
  float rs = rsqrtf(var + 1e-5f);
  int c = lane * 8;
  for (int j = 0; j < 8; j++)
    out[base + j] = (y[j] - mu) * rs * gamma[c + j] + beta[c + j];
}

extern "C" void kernel_launch(void* const* d_in, const int* in_sizes, int n_in,
                              void* d_out, int out_size, void* d_ws, size_t ws_size,
                              hipStream_t stream) {
  const float* x     = (const float*)d_in[0];
  const float* Wq    = (const float*)d_in[1];
  const float* bq    = (const float*)d_in[2];
  const float* Wk    = (const float*)d_in[3];
  const float* bk    = (const float*)d_in[4];
  const float* Wv    = (const float*)d_in[5];
  const float* bv    = (const float*)d_in[6];
  const float* gamma = (const float*)d_in[7];
  const float* beta  = (const float*)d_in[8];
  float* out = (float*)d_out;

  char* ws = (char*)d_ws;
  float*          ows  = (float*)(ws + 0);
  unsigned short* xb   = (unsigned short*)(ws + 0);
  unsigned short* qws  = (unsigned short*)(ws + 33554432);
  unsigned short* kws  = (unsigned short*)(ws + 35651584);
  unsigned short* vt   = (unsigned short*)(ws + 37748736);
  unsigned short* Wt   = (unsigned short*)(ws + 54525952);
  float*          bias = (float*)(ws + 55181312);

  cast_x_kernel<<<8192, 256, 0, stream>>>(x, xb);
  prep_w_kernel<<<640, 256, 0, stream>>>(Wq, bq, Wk, bk, Wv, bv, Wt, bias);
  proj_kernel<<<dim3(10, 256), 256, 0, stream>>>(xb, Wt, bias, qws, kws, vt);
  attn_kernel<<<dim3(64, 4, NB), 256, 0, stream>>>(qws, kws, vt, ows);
  ln_kernel<<<4096, 256, 0, stream>>>(x, ows, gamma, beta, out);
}

// Round 4
// 215.010 us; speedup vs baseline: 4.0451x; 4.0451x over previous
//
#include <hip/hip_runtime.h>

#define NB 4
#define SEQ 4096
#define DM 512
#define DA 64

typedef __attribute__((ext_vector_type(8))) short bf16x8;
typedef __attribute__((ext_vector_type(4))) float f32x4;
typedef __attribute__((address_space(3))) unsigned int lds_u32;
typedef const __attribute__((address_space(1))) unsigned int glb_u32;

__device__ __forceinline__ unsigned short f2bf(float f) {
  unsigned u = __float_as_uint(f);
  u += 0x7fffu + ((u >> 16) & 1u);
  return (unsigned short)(u >> 16);
}

__device__ __forceinline__ unsigned cvt_pk_bf16(float lo, float hi) {
  unsigned r;
  asm("v_cvt_pk_bf16_f32 %0, %1, %2" : "=v"(r) : "v"(lo), "v"(hi));
  return r;
}

__device__ __forceinline__ void g2lds16(const unsigned short* g, unsigned short* l) {
  __builtin_amdgcn_global_load_lds((glb_u32*)g, (lds_u32*)l, 16, 0, 0);
}

// ---------------- Kernel 1: cast x (f32) -> xb (bf16) ----------------
__global__ void cast_x_kernel(const float* __restrict__ x, unsigned short* __restrict__ xb) {
  size_t i = ((size_t)blockIdx.x * blockDim.x + threadIdx.x) * 4;
  float4 v = *(const float4*)(x + i);
  ushort4 o;
  o.x = f2bf(v.x); o.y = f2bf(v.y); o.z = f2bf(v.z); o.w = f2bf(v.w);
  *(ushort4*)(xb + i) = o;
}

// ------------- Kernel 2: build Wt[640][512] bf16 (transposed) + bias[640] -------------
__global__ void prep_w_kernel(const float* __restrict__ Wq, const float* __restrict__ bq,
                              const float* __restrict__ Wk, const float* __restrict__ bk,
                              const float* __restrict__ Wv, const float* __restrict__ bv,
                              unsigned short* __restrict__ Wt, float* __restrict__ bias) {
  int n = blockIdx.x;  // 0..639
  for (int k = threadIdx.x; k < DM; k += blockDim.x) {
    float w;
    if (n < 64)       w = Wq[(size_t)k * DA + n];
    else if (n < 128) w = Wk[(size_t)k * DA + (n - 64)];
    else              w = Wv[(size_t)k * DM + (n - 128)];
    Wt[(size_t)n * DM + k] = f2bf(w);
  }
  if (threadIdx.x == 0)
    bias[n] = (n < 64) ? bq[n] : (n < 128) ? bk[n - 64] : bv[n - 128];
}

// ------------- Kernel 3: projection GEMM  out[16384 x 640] = xb @ Wt^T + bias -------------
// n<64 -> q[S][64], n<128 -> k[S][64], else vt[512][S] transposed V with keys
// PERMUTED within each 32-chunk (pos 8g+j) so attn PV A-frag needs no shuffle.
__launch_bounds__(256)
__global__ void proj_kernel(const unsigned short* __restrict__ xb,
                            const unsigned short* __restrict__ Wt,
                            const float* __restrict__ bias,
                            unsigned short* __restrict__ qws,
                            unsigned short* __restrict__ kws,
                              unsigned short* __restrict__ vt) {
  int ctb = blockIdx.x;
  int rtb = blockIdx.y;
  int tid = threadIdx.x;
  int wid = tid >> 6, lane = tid & 63;
  int g = lane >> 4, c15 = lane & 15;
  int wr = wid >> 1, wc = wid & 1;
  int rbase = rtb * 64 + wr * 32;
  int cbase = ctb * 64 + wc * 32;

  f32x4 acc[2][2];
  for (int i = 0; i < 2; i++) for (int j = 0; j < 2; j++) acc[i][j] = (f32x4)0.0f;

  for (int kk = 0; kk < DM; kk += 32) {
    bf16x8 a[2], bb[2];
    for (int i = 0; i < 2; i++)
      a[i] = *(const bf16x8*)(xb + (size_t)(rbase + i * 16 + c15) * DM + kk + g * 8);
    for (int j = 0; j < 2; j++)
      bb[j] = *(const bf16x8*)(Wt + (size_t)(cbase + j * 16 + c15) * DM + kk + g * 8);
    for (int i = 0; i < 2; i++)
      for (int j = 0; j < 2; j++)
        acc[i][j] = __builtin_amdgcn_mfma_f32_16x16x32_bf16(a[i], bb[j], acc[i][j], 0, 0, 0);
  }

  for (int i = 0; i < 2; i++) {
    for (int j = 0; j < 2; j++) {
      int n = cbase + j * 16 + c15;
      float bv_ = bias[n];
      for (int r = 0; r < 4; r++) {
        int R = rbase + i * 16 + g * 4 + r;
        float val = acc[i][j][r] + bv_;
        unsigned short h = f2bf(val);
        if (n < 64)        qws[(size_t)R * DA + n] = h;
        else if (n < 128)  kws[(size_t)R * DA + (n - 64)] = h;
        else {
          int b = R >> 12, s = R & (SEQ - 1);
          int c = s & 31;
          int pos = (c < 16) ? (((c >> 2) << 3) | (c & 3))
                             : ((((c & 15) >> 2) << 3) | 4 | (c & 3));
          vt[((size_t)b * DM + (n - 128)) * SEQ + (s & ~31) + pos] = h;
        }
      }
    }
  }
}

// ------------- Kernel 4: causal flash attention, LDS-staged K/V -------------
// Grid (8, 64): x=(b,dh): XCD-affine; y->qblk paired long/short. Block 256 thr = 4 waves.
// Block: 64 q-rows x 256 dv. Per iter 64 keys: K(8KB)+V^T(32KB) staged to LDS
// (global_load_lds, double-buffered, XOR-swizzled via pre-swizzled source addr).
// Wave: 16 rows, S^T=mfma(K,Q), in-reg softmax, cvt_pk P -> PV (V keys pre-permuted).
__launch_bounds__(256, 2)
__global__ void attn_kernel(const unsigned short* __restrict__ qws,
                            const unsigned short* __restrict__ kws,
                            const unsigned short* __restrict__ vt,
                            float* __restrict__ ows) {
  int bd = blockIdx.x;            // b*2+dh
  int b = bd >> 1, dh = bd & 1;
  int dvb = dh * 256;
  int y = blockIdx.y;
  int qblk = (y < 32) ? y : 95 - y;     // pair long+short on same CU slot
  int qb = qblk * 64;
  int tid = threadIdx.x;
  int wid = tid >> 6, lane = tid & 63;
  int g = lane >> 4, c15 = lane & 15;
  int qrow16 = qb + wid * 16;
  int qsrc = (g << 4) | (g << 2);       // lane 20g (+r) holds stats for q-row 4g+r

  // LDS: 2 buffers x (V 256x64 ushort = 16384 | K 64x64 ushort = 4096) = 80KB
  __shared__ unsigned short lds[40960];

  // staging source bases (pre-swizzled: c8x = (tid&7) ^ ((tid>>3)&7))
  int row0 = tid >> 3, c8x = (tid & 7) ^ ((tid >> 3) & 7);
  const unsigned short* srcV = vt + ((size_t)(b * DM + dvb + row0)) * SEQ + c8x * 8;
  const unsigned short* srcK = kws + ((size_t)b * SEQ + row0) * DA + c8x * 8;
  int ldsV = wid * 512 + (tid & 63) * 0;  // base handled per-round below
  (void)ldsV;

  auto stage = [&](int t, int kt) {
    unsigned short* Vb = &lds[t * 20480];
    unsigned short* Kb = &lds[t * 20480 + 16384];
    for (int r = 0; r < 8; r++)
      g2lds16(srcV + (size_t)(r * 32) * SEQ + kt, &Vb[r * 2048 + wid * 512]);
    for (int r = 0; r < 2; r++)
      g2lds16(srcK + (size_t)(r * 32 + kt) * DA, &Kb[r * 2048 + wid * 512]);
  };

  bf16x8 qf[2];
  for (int kc2 = 0; kc2 < 2; kc2++)
    qf[kc2] = *(const bf16x8*)(qws + ((size_t)b * SEQ + qrow16 + c15) * DA + kc2 * 32 + g * 8);

  f32x4 acc[16];
  for (int n = 0; n < 16; n++) acc[n] = (f32x4)0.0f;
  float m_run = -1e30f, l_run = 0.0f;

  int nkt = qblk + 1;

  stage(0, 0);
  __syncthreads();
  int t = 0;
  for (int i = 0; i < nkt; i++) {
    int kt = i * 64;
    if (i + 1 < nkt) stage(t ^ 1, kt + 64);

    const unsigned short* Vb = &lds[t * 20480];
    const unsigned short* Kb = &lds[t * 20480 + 16384];
    int sw = c15 & 7;

    // ---- S^T: 64 keys x 16 q ----
    f32x4 sc[4];
    for (int ct = 0; ct < 4; ct++) sc[ct] = (f32x4)0.0f;
    for (int kc2 = 0; kc2 < 2; kc2++)
      for (int ct = 0; ct < 4; ct++) {
        int row = ct * 16 + c15;
        bf16x8 kf = *(const bf16x8*)&Kb[row * 64 + (((kc2 << 2) | g) ^ sw) * 8];
        sc[ct] = __builtin_amdgcn_mfma_f32_16x16x32_bf16(kf, qf[kc2], sc[ct], 0, 0, 0);
      }
    if (i == nkt - 1) {             // only the diagonal tile needs masking
      int qrow = qrow16 + c15;
      for (int ct = 0; ct < 4; ct++)
        for (int r = 0; r < 4; r++)
          if (kt + ct * 16 + 4 * g + r > qrow) sc[ct][r] = -1e30f;
    }
    // ---- softmax over 16 in-lane values + 2 shfl ----
    float mv = -1e30f;
    for (int ct = 0; ct < 4; ct++)
      for (int r = 0; r < 4; r++) mv = fmaxf(mv, sc[ct][r]);
    mv = fmaxf(mv, __shfl_xor(mv, 16));
    mv = fmaxf(mv, __shfl_xor(mv, 32));
    float mn = fmaxf(m_run, mv);
    float sum = 0.0f;
    for (int ct = 0; ct < 4; ct++)
      for (int r = 0; r < 4; r++) {
        float p = __expf(sc[ct][r] - mn);
        sc[ct][r] = p;
        sum += p;
      }
    sum += __shfl_xor(sum, 16);
    sum += __shfl_xor(sum, 32);
    float scl = __expf(m_run - mn);
    m_run = mn;
    l_run = l_run * scl + sum;
    float sclr[4];
    for (int r = 0; r < 4; r++) sclr[r] = __shfl(scl, qsrc + r);
    for (int n = 0; n < 16; n++)
      for (int r = 0; r < 4; r++) acc[n][r] *= sclr[r];
    // ---- PV: P[16 x 64] x V^T[256 dv][64 keys] ----
    for (int kc = 0; kc < 2; kc++) {
      union { int i4[4]; bf16x8 h; } pu;
      pu.i4[0] = cvt_pk_bf16(sc[2 * kc][0], sc[2 * kc][1]);
      pu.i4[1] = cvt_pk_bf16(sc[2 * kc][2], sc[2 * kc][3]);
      pu.i4[2] = cvt_pk_bf16(sc[2 * kc + 1][0], sc[2 * kc + 1][1]);
      pu.i4[3] = cvt_pk_bf16(sc[2 * kc + 1][2], sc[2 * kc + 1][3]);
      bf16x8 pa = pu.h;
      for (int n = 0; n < 16; n++) {
        int row = n * 16 + c15;
        bf16x8 vb = *(const bf16x8*)&Vb[row * 64 + (((kc << 2) | g) ^ sw) * 8];
        acc[n] = __builtin_amdgcn_mfma_f32_16x16x32_bf16(pa, vb, acc[n], 0, 0, 0);
      }
    }
    __syncthreads();
    t ^= 1;
  }

  float inv[4];
  for (int r = 0; r < 4; r++) inv[r] = 1.0f / __shfl(l_run, qsrc + r);
  for (int n = 0; n < 16; n++)
    for (int r = 0; r < 4; r++)
      ows[((size_t)b * SEQ + qrow16 + 4 * g + r) * DM + dvb + n * 16 + c15] = acc[n][r] * inv[r];
}

// ------------- Kernel 5: residual + LayerNorm (wave per row) -------------
__launch_bounds__(256)
__global__ void ln_kernel(const float* __restrict__ x, const float* __restrict__ o,
                          const float* __restrict__ gamma, const float* __restrict__ beta,
                          float* __restrict__ out) {
  int wid = threadIdx.x >> 6, lane = threadIdx.x & 63;
  size_t row = (size_t)blockIdx.x * 4 + wid;
  size_t base = row * DM + lane * 8;
  float4 xa = *(const float4*)(x + base);
  float4 xb2 = *(const float4*)(x + base + 4);
  float4 oa = *(const float4*)(o + base);
  float4 ob = *(const float4*)(o + base + 4);
  float y[8] = {xa.x + oa.x, xa.y + oa.y, xa.z + oa.z, xa.w + oa.w,
                xb2.x + ob.x, xb2.y + ob.y, xb2.z + ob.z, xb2.w + ob.w};
  float s1 = 0.0f, s2 = 0.0f;
  for (int j = 0; j < 8; j++) { s1 += y[j]; s2 += y[j] * y[j]; }
  for (int m = 1; m < 64; m <<= 1) { s1 += __shfl_xor(s1, m); s2 += __shfl_xor(s2, m); }
  float mu = s1 * (1.0f / DM);
  float var = s2 * (1.0f / DM) - mu * mu;
  float rs = rsqrtf(var + 1e-5f);
  int c = lane * 8;
  for (int j = 0; j < 8; j++)
    out[base + j] = (y[j] - mu) * rs * gamma[c + j] + beta[c + j];
}

extern "C" void kernel_launch(void* const* d_in, const int* in_sizes, int n_in,
                              void* d_out, int out_size, void* d_ws, size_t ws_size,
                              hipStream_t stream) {
  const float* x     = (const float*)d_in[0];
  const float* Wq    = (const float*)d_in[1];
  const float* bq    = (const float*)d_in[2];
  const float* Wk    = (const float*)d_in[3];
  const float* bk    = (const float*)d_in[4];
  const float* Wv    = (const float*)d_in[5];
  const float* bv    = (const float*)d_in[6];
  const float* gamma = (const float*)d_in[7];
  const float* beta  = (const float*)d_in[8];
  float* out = (float*)d_out;

  char* ws = (char*)d_ws;
  float*          ows  = (float*)(ws + 0);
  unsigned short* xb   = (unsigned short*)(ws + 0);   // aliases ows; dead before attn
  unsigned short* qws  = (unsigned short*)(ws + 33554432);
  unsigned short* kws  = (unsigned short*)(ws + 35651584);
  unsigned short* vt   = (unsigned short*)(ws + 37748736);
  unsigned short* Wt   = (unsigned short*)(ws + 54525952);
  float*          bias = (float*)(ws + 55181312);

  cast_x_kernel<<<8192, 256, 0, stream>>>(x, xb);
  prep_w_kernel<<<640, 256, 0, stream>>>(Wq, bq, Wk, bk, Wv, bv, Wt, bias);
  proj_kernel<<<dim3(10, 256), 256, 0, stream>>>(xb, Wt, bias, qws, kws, vt);
  attn_kernel<<<dim3(8, 64), 256, 0, stream>>>(qws, kws, vt, ows);
  ln_kernel<<<4096, 256, 0, stream>>>(x, ows, gamma, beta, out);
}